// Round 5
// baseline (302.855 us; speedup 1.0000x reference)
//
#include <hip/hip_runtime.h>
#include <hip/hip_bf16.h>
#include <cstdint>

// SpatialAttentionModule: x[4,256,64,64] fp32; q=Wq x, k=Wk x, v=Wv x (1x1 conv);
// energy = q^T k per batch (N=4096), softmax over j, out = gamma*(v@attn^T) + x.
//
// Round-5: k_attn restructured to remove the 4x cross-wave fragment redundancy.
// S-phase: wave w computes keys [w*16,w*16+16) x all 64 queries (Q in regs,
// K-frags read once per block). PV-phase: wave w computes channels [w*64,..)
// x all 64 queries (V/P frags read once per block per wave-slice). Softmax
// max/sum exchanged block-wide via small LDS buffer; 2 barriers/tile.
// LDS reads: 66 -> 24 ds_read_b128 per wave-tile. exp2f -> __expf (2 VALU).
// fp16 pipeline (absmax 0.031 in R4, 3.3x margin). DMA dbuf staging kept.
// MFMA layouts (HW-verified, learn_hip m89/m91, dtype-independent):
//   A[m=lane&15][k=quad*8+j], B[k=quad*8+j][n=lane&15], C/D: col=lane&15, row=quad*4+reg.

#define C_DIM 256
#define N_DIM 4096
#define B_DIM 4

typedef _Float16 f16;
typedef f16 f16x8 __attribute__((ext_vector_type(8)));
typedef f16 f16x4 __attribute__((ext_vector_type(4)));
typedef float f32x4 __attribute__((ext_vector_type(4)));

__device__ __forceinline__ void dma16(const f16* g, f16* l) {
  __builtin_amdgcn_global_load_lds(
      (const __attribute__((address_space(1))) unsigned int*)g,
      (__attribute__((address_space(3))) unsigned int*)l, 16, 0, 0);
}

// ---------------- prep: transpose-cast x -> xs fp16 [B*N][256] ----------------
__global__ __launch_bounds__(256) void k_prep_xs(const float* __restrict__ x,
                                                 f16* __restrict__ xs) {
  __shared__ float tile[64][65];
  const int b = blockIdx.z, nb = blockIdx.x * 64, cb = blockIdx.y * 64;
  const float* xb = x + (size_t)b * C_DIM * N_DIM;
  for (int i = threadIdx.x; i < 64 * 64; i += 256) {
    int c = i >> 6, n = i & 63;
    tile[c][n] = xb[(size_t)(cb + c) * N_DIM + nb + n];
  }
  __syncthreads();
  f16* xsb = xs + (size_t)b * N_DIM * C_DIM;
  for (int i = threadIdx.x; i < 64 * 64; i += 256) {
    int n = i >> 6, c = i & 63;
    xsb[(size_t)(nb + n) * C_DIM + cb + c] = (f16)tile[c][n];
  }
}

// ---------------- prep: cast 3 weight matrices -> fp16 [3*256][256] ----------------
__global__ __launch_bounds__(256) void k_cast_w(const float* __restrict__ Wq,
                                                const float* __restrict__ Wk,
                                                const float* __restrict__ Wv,
                                                f16* __restrict__ Wh) {
  int i = blockIdx.x * 256 + threadIdx.x;
  int sel = i >> 16, j = i & 65535;
  const float* s = (sel == 0) ? Wq : (sel == 1) ? Wk : Wv;
  Wh[i] = (f16)s[j];
}

// ---------------- QKV projection GEMMs (fp16, K=256) ----------------
__global__ __launch_bounds__(256) void k_proj(const f16* __restrict__ xs,
                                              const f16* __restrict__ Wh,
                                              const float* __restrict__ bq,
                                              const float* __restrict__ bk,
                                              const float* __restrict__ bv,
                                              f16* __restrict__ Qh,
                                              f16* __restrict__ Kh,
                                              f16* __restrict__ Vh) {
  const int z = blockIdx.y;
  const int w = threadIdx.x >> 6, lane = threadIdx.x & 63;
  const int quad = lane >> 4, li = lane & 15;
  const f16* W = Wh + (size_t)z * 65536;
  const float* bias = (z == 0) ? bq : (z == 1) ? bk : bv;

  if (z < 2) {
    f16* out = (z == 0) ? Qh : Kh;
    const int g0 = (blockIdx.x * 4 + w) * 16;
    f16x8 a[8];
    const f16* arow = xs + (size_t)(g0 + li) * C_DIM + quad * 8;
#pragma unroll
    for (int kf = 0; kf < 8; kf++) a[kf] = *(const f16x8*)(arow + kf * 32);
    for (int ot = 0; ot < 16; ot++) {
      f32x4 acc = {0.f, 0.f, 0.f, 0.f};
      const f16* brow = W + (size_t)(ot * 16 + li) * C_DIM + quad * 8;
#pragma unroll
      for (int kf = 0; kf < 8; kf++) {
        f16x8 bf = *(const f16x8*)(brow + kf * 32);
        acc = __builtin_amdgcn_mfma_f32_16x16x32_f16(a[kf], bf, acc, 0, 0, 0);
      }
      float bb = bias[ot * 16 + li];
      f16* orow = out + (size_t)g0 * C_DIM + ot * 16 + li;
#pragma unroll
      for (int r = 0; r < 4; r++)
        orow[(size_t)(quad * 4 + r) * C_DIM] = (f16)(acc[r] + bb);
    }
  } else {
    const int t = blockIdx.x * 4 + w;
    const int b = t >> 8, j0 = (t & 255) * 16;
    f16x8 bfr[8];
    const f16* brow = xs + (size_t)(b * N_DIM + j0 + li) * C_DIM + quad * 8;
#pragma unroll
    for (int kf = 0; kf < 8; kf++) bfr[kf] = *(const f16x8*)(brow + kf * 32);
    for (int ot = 0; ot < 16; ot++) {
      f32x4 acc = {0.f, 0.f, 0.f, 0.f};
      const f16* arow = W + (size_t)(ot * 16 + li) * C_DIM + quad * 8;
#pragma unroll
      for (int kf = 0; kf < 8; kf++) {
        f16x8 af = *(const f16x8*)(arow + kf * 32);
        acc = __builtin_amdgcn_mfma_f32_16x16x32_f16(af, bfr[kf], acc, 0, 0, 0);
      }
      f16* obase = Vh + ((size_t)(b * C_DIM + ot * 16 + quad * 4)) * N_DIM + j0 + li;
#pragma unroll
      for (int r = 0; r < 4; r++) {
        float bb = bias[ot * 16 + quad * 4 + r];
        obase[(size_t)r * N_DIM] = (f16)(acc[r] + bb);
      }
    }
  }
}

// ---------------- fused attention ----------------
// grid (64,4): 64-query block, batch; 4 waves.
// Tile = 64 keys. S: wave w owns keys [w*16,..). PV: wave w owns channels
// [w*64,..). P (64q x 64j) and max/sum exchange live in shared LDS.
// LDS layouts (f16 units):
//   K: phys(r,k) = (r>>1)*528 + (r&1)*256 + k       (DMA span = 2 rows)
//   V: phys(c,j) = (c>>3)*528 + (c&7)*64 + j        (DMA span = 8 rows)
//   P: [q][j] row stride 72 f16 (144 B, 16B-aligned)
//   mx: float[64][4] exchange buffer
#define JT 64
#define NT (N_DIM / JT)
#define K0_OFF 0
#define K1_OFF 16896
#define V0_OFF 33792
#define V1_OFF 50688
#define P_OFF  67584
#define PSTR 72
#define MX_OFF 72192          // f16 units; 512 floats
#define SMEM_F16 73216        // 146432 B

__global__ __launch_bounds__(256, 1) void k_attn(const f16* __restrict__ Qh,
                                                 const f16* __restrict__ Kh,
                                                 const f16* __restrict__ Vh,
                                                 const float* __restrict__ x,
                                                 const float* __restrict__ gamma_p,
                                                 float* __restrict__ out) {
  __shared__ __align__(16) f16 smem[SMEM_F16];
  const int b = blockIdx.y;
  const int tid = threadIdx.x;
  const int w = tid >> 6, lane = tid & 63;
  const int quad = lane >> 4, li = lane & 15;
  const int qg0 = blockIdx.x * 64;

  const f16* Kb = Kh + (size_t)b * N_DIM * C_DIM;
  const f16* Vb = Vh + (size_t)b * C_DIM * N_DIM;
  float* mx = (float*)(smem + MX_OFF);
  f16* Pq = smem + P_OFF;

  // Q: all 64 queries of the block as B-operand frags (held in registers)
  f16x8 qf[4][8];
#pragma unroll
  for (int cb = 0; cb < 4; cb++) {
    const f16* qrow = Qh + (size_t)(b * N_DIM + qg0 + cb * 16 + li) * C_DIM + quad * 8;
#pragma unroll
    for (int kf = 0; kf < 8; kf++) qf[cb][kf] = *(const f16x8*)(qrow + kf * 32);
  }

  float m[4] = {-3.0e38f, -3.0e38f, -3.0e38f, -3.0e38f};
  float l[4] = {0.f, 0.f, 0.f, 0.f};
  f32x4 acc[4][4];   // [ctb][cb]
#pragma unroll
  for (int a = 0; a < 4; a++)
#pragma unroll
    for (int c = 0; c < 4; c++) acc[a][c] = (f32x4){0.f, 0.f, 0.f, 0.f};

  // prologue: DMA tile 0 -> buf0
#pragma unroll
  for (int it = 0; it < 8; it++) {
    int p = w * 8 + it;
    dma16(Kb + (size_t)(2 * p + (lane >> 5)) * C_DIM + (lane & 31) * 8,
          smem + K0_OFF + p * 528);
    dma16(Vb + (size_t)(p * 8 + (lane >> 3)) * N_DIM + (lane & 7) * 8,
          smem + V0_OFF + p * 528);
  }
  __syncthreads();

  for (int t = 0; t < NT; t++) {
    const f16* Kc = smem + ((t & 1) ? K1_OFF : K0_OFF);
    const f16* Vc = smem + ((t & 1) ? V1_OFF : V0_OFF);

    // ---- S: wave's 16 keys x 64 queries ----
    f16x8 kfr[8];
    {
      const int r = w * 16 + li;
      const f16* krow = Kc + (r >> 1) * 528 + (r & 1) * 256 + quad * 8;
#pragma unroll
      for (int kf = 0; kf < 8; kf++) kfr[kf] = *(const f16x8*)(krow + kf * 32);
    }
    f32x4 s[4];
#pragma unroll
    for (int cb = 0; cb < 4; cb++) {
      f32x4 ss = {0.f, 0.f, 0.f, 0.f};
#pragma unroll
      for (int kf = 0; kf < 8; kf++)
        ss = __builtin_amdgcn_mfma_f32_16x16x32_f16(kfr[kf], qf[cb][kf], ss, 0, 0, 0);
      s[cb] = ss;
    }

    // wave-partial max per query -> LDS exchange
    float tmw[4];
#pragma unroll
    for (int cb = 0; cb < 4; cb++) {
      float tm = fmaxf(fmaxf(s[cb][0], s[cb][1]), fmaxf(s[cb][2], s[cb][3]));
      tm = fmaxf(tm, __shfl_xor(tm, 16));
      tm = fmaxf(tm, __shfl_xor(tm, 32));
      tmw[cb] = tm;
    }
    if (lane < 16) {
#pragma unroll
      for (int cb = 0; cb < 4; cb++) mx[(cb * 16 + lane) * 4 + w] = tmw[cb];
    }
    __syncthreads();                       // barrier A (also: prev DMA known done)

    // issue DMA for tile t+1 (safe: all waves past PV(t-1) & S-reads of dest bufs)
    if (t + 1 < NT) {
      f16* Kn = smem + ((t & 1) ? K0_OFF : K1_OFF);
      f16* Vn = smem + ((t & 1) ? V0_OFF : V1_OFF);
      const f16* kg = Kb + (size_t)(t + 1) * JT * C_DIM;
      const f16* vg = Vb + (t + 1) * JT;
#pragma unroll
      for (int it = 0; it < 8; it++) {
        int p = w * 8 + it;
        dma16(kg + (size_t)(2 * p + (lane >> 5)) * C_DIM + (lane & 31) * 8,
              Kn + p * 528);
        dma16(vg + (size_t)(p * 8 + (lane >> 3)) * N_DIM + (lane & 7) * 8,
              Vn + p * 528);
      }
    }

    // block max, alpha, rescale, p, P-write
    float nm[4], al[4];
    bool need = false;
#pragma unroll
    for (int cb = 0; cb < 4; cb++) {
      float4 mm = *(const float4*)&mx[(cb * 16 + li) * 4];
      float bm = fmaxf(fmaxf(mm.x, mm.y), fmaxf(mm.z, mm.w));
      nm[cb] = fmaxf(m[cb], bm);
      al[cb] = __expf(m[cb] - nm[cb]);
      need |= (nm[cb] > m[cb]);
      m[cb] = nm[cb];
    }
    if (__any(need)) {
#pragma unroll
      for (int cb = 0; cb < 4; cb++) {
        l[cb] *= al[cb];
#pragma unroll
        for (int ctb = 0; ctb < 4; ctb++) acc[ctb][cb] *= al[cb];
      }
    }
#pragma unroll
    for (int cb = 0; cb < 4; cb++) {
      float p0 = __expf(s[cb][0] - m[cb]);
      float p1 = __expf(s[cb][1] - m[cb]);
      float p2 = __expf(s[cb][2] - m[cb]);
      float p3 = __expf(s[cb][3] - m[cb]);
      l[cb] += (p0 + p1) + (p2 + p3);
      *(f16x4*)(Pq + (cb * 16 + li) * PSTR + w * 16 + quad * 4) =
          (f16x4){(f16)p0, (f16)p1, (f16)p2, (f16)p3};
    }
    __syncthreads();                       // barrier B (P visible; DMA drained)

    // ---- PV: wave's 64 channels x 64 queries over 64 keys ----
#pragma unroll
    for (int kf2 = 0; kf2 < 2; kf2++) {
      f16x8 vf[4];
#pragma unroll
      for (int ctb = 0; ctb < 4; ctb++) {
        int c = w * 64 + ctb * 16 + li;
        vf[ctb] = *(const f16x8*)(Vc + (c >> 3) * 528 + (c & 7) * 64 + kf2 * 32 + quad * 8);
      }
#pragma unroll
      for (int cb = 0; cb < 4; cb++) {
        f16x8 pf = *(const f16x8*)(Pq + (cb * 16 + li) * PSTR + kf2 * 32 + quad * 8);
#pragma unroll
        for (int ctb = 0; ctb < 4; ctb++)
          acc[ctb][cb] = __builtin_amdgcn_mfma_f32_16x16x32_f16(vf[ctb], pf, acc[ctb][cb], 0, 0, 0);
      }
    }
    // no barrier here: next tile's mx/P writes are fenced by barrier A/B logic
  }

  // final l: quad-reduce then cross-wave sum via mx
#pragma unroll
  for (int cb = 0; cb < 4; cb++) {
    l[cb] += __shfl_xor(l[cb], 16);
    l[cb] += __shfl_xor(l[cb], 32);
  }
  __syncthreads();
  if (lane < 16) {
#pragma unroll
    for (int cb = 0; cb < 4; cb++) mx[(cb * 16 + lane) * 4 + w] = l[cb];
  }
  __syncthreads();
  const float g = gamma_p[0];
  float scale[4];
#pragma unroll
  for (int cb = 0; cb < 4; cb++) {
    float4 ll = *(const float4*)&mx[(cb * 16 + li) * 4];
    scale[cb] = g / (((ll.x + ll.y) + (ll.z + ll.w)));
  }

  const float* xb = x + (size_t)b * C_DIM * N_DIM;
  float* ob = out + (size_t)b * C_DIM * N_DIM;
#pragma unroll
  for (int ctb = 0; ctb < 4; ctb++) {
#pragma unroll
    for (int r = 0; r < 4; r++) {
      int ch = w * 64 + ctb * 16 + quad * 4 + r;
#pragma unroll
      for (int cb = 0; cb < 4; cb++) {
        size_t off = (size_t)ch * N_DIM + qg0 + cb * 16 + li;
        ob[off] = acc[ctb][cb][r] * scale[cb] + xb[off];
      }
    }
  }
}

extern "C" void kernel_launch(void* const* d_in, const int* in_sizes, int n_in,
                              void* d_out, int out_size, void* d_ws, size_t ws_size,
                              hipStream_t stream) {
  const float* x     = (const float*)d_in[0];
  const float* Wq    = (const float*)d_in[1];
  const float* bq    = (const float*)d_in[2];
  const float* Wk    = (const float*)d_in[3];
  const float* bk    = (const float*)d_in[4];
  const float* Wv    = (const float*)d_in[5];
  const float* bv    = (const float*)d_in[6];
  const float* gamma = (const float*)d_in[7];
  float* out = (float*)d_out;

  // workspace: xs 8MB | Qh 8MB | Kh 8MB | Vh 8MB | Wh 384KB  (~32.4 MB)
  char* ws = (char*)d_ws;
  f16* xs = (f16*)(ws);
  f16* Qh = (f16*)(ws + (size_t)8  * 1024 * 1024);
  f16* Kh = (f16*)(ws + (size_t)16 * 1024 * 1024);
  f16* Vh = (f16*)(ws + (size_t)24 * 1024 * 1024);
  f16* Wh = (f16*)(ws + (size_t)32 * 1024 * 1024);

  k_prep_xs<<<dim3(64, 4, 4), 256, 0, stream>>>(x, xs);
  k_cast_w<<<dim3(768), 256, 0, stream>>>(Wq, Wk, Wv, Wh);
  k_proj<<<dim3(256, 3), 256, 0, stream>>>(xs, Wh, bq, bk, bv, Qh, Kh, Vh);
  k_attn<<<dim3(64, 4), 256, 0, stream>>>(Qh, Kh, Vh, x, gamma, out);
}